// Round 5
// baseline (104.779 us; speedup 1.0000x reference)
//
#include <hip/hip_runtime.h>
#include <math.h>

#define NN 256
#define LL 4096
#define DL 64
#define DC 128
#define KS 15
#define LOUT (LL - KS + 1)   // 4082
#define RSQRT_DC 0.08838834764831843f
#define INV_LOUT (1.0f / (float)LOUT)

// ws layout (4-byte units):
#define WS_CTB   0         // 60*128 floats
#define WS_QC    7680      // 60*128
#define WS_KC    15360     // 60*128
#define WS_G     23040     // 60*128
#define WS_S0    30720     // 60 (+pad)
#define WS_BB    30784     // 60 (+pad)
#define WS_B0    30848     // 1
#define WS_OUTB  30976     // 128
#define WS_PACK  31104     // 256*256 uints
#define WS_CNT   96640     // 256*4 ints

// ---------------- K1: token pack+counts (blocks 0..255) + ctb (blocks 256..383) ----------------
__global__ __launch_bounds__(256) void prep1_kernel(const int* __restrict__ tokens,
                                                    const float* __restrict__ emb,
                                                    const float* __restrict__ conv_w,
                                                    float* __restrict__ ws) {
    const int b = blockIdx.x, tid = threadIdx.x;
    if (b < NN) {
        __shared__ int totw[4][4];
        const int n = b;
        const int4* tv = (const int4*)(tokens + (size_t)n * LL) + tid * 4;
        unsigned w = 0;
#pragma unroll
        for (int m = 0; m < 4; ++m) {
            int4 t4 = tv[m];
            w |= ((unsigned)t4.x | ((unsigned)t4.y << 2) |
                  ((unsigned)t4.z << 4) | ((unsigned)t4.w << 6)) << (8 * m);
        }
        ((unsigned*)ws)[WS_PACK + n * 256 + tid] = w;
        int c0, c1, c2, c3;
        unsigned y, z;
        y = w;               z = (y | (y >> 1)) & 0x55555555u; c0 = 16 - __popc(z);
        y = w ^ 0x55555555u; z = (y | (y >> 1)) & 0x55555555u; c1 = 16 - __popc(z);
        y = w ^ 0xAAAAAAAAu; z = (y | (y >> 1)) & 0x55555555u; c2 = 16 - __popc(z);
        y = w ^ 0xFFFFFFFFu; z = (y | (y >> 1)) & 0x55555555u; c3 = 16 - __popc(z);
#pragma unroll
        for (int off = 32; off > 0; off >>= 1) {
            c0 += __shfl_down(c0, off, 64); c1 += __shfl_down(c1, off, 64);
            c2 += __shfl_down(c2, off, 64); c3 += __shfl_down(c3, off, 64);
        }
        if ((tid & 63) == 0) {
            const int wv = tid >> 6;
            totw[wv][0] = c0; totw[wv][1] = c1; totw[wv][2] = c2; totw[wv][3] = c3;
        }
        __syncthreads();
        if (tid < 4)
            ((int*)ws)[WS_CNT + n * 4 + tid] =
                totw[0][tid] + totw[1][tid] + totw[2][tid] + totw[3][tid];
    } else {
        const int c = b - NN;
        __shared__ float wsm[DL][16];
        __shared__ float es[4][DL];
        const float* wsrc = conv_w + (size_t)c * (DL * KS);
        for (int idx = tid; idx < DL * KS; idx += 256) wsm[idx / KS][idx % KS] = wsrc[idx];
        es[tid >> 6][tid & 63] = emb[tid];
        __syncthreads();
        if (tid < 60) {
            const int v = tid / KS, k = tid % KS;
            float s = 0.f;
#pragma unroll
            for (int i = 0; i < DL; ++i) s += es[v][i] * wsm[i][k];
            ws[WS_CTB + tid * DC + c] = s;
        }
    }
}

// ---------------- K2: weight-algebra precompute ----------------
// blocks 0..59: QC[j], KC[j], G[j], s0[j], bb[j].  block 60: b0, outb.
__global__ __launch_bounds__(128) void prep2_kernel(
    const float* __restrict__ conv_b,
    const float* __restrict__ Wq, const float* __restrict__ bq,
    const float* __restrict__ Wk, const float* __restrict__ bk,
    const float* __restrict__ Wv, const float* __restrict__ bv,
    float* __restrict__ ws) {
    const int j = blockIdx.x, c = threadIdx.x;
    __shared__ float cbL[DC];
    __shared__ float red2a[2], red2b[2];
    cbL[c] = conv_b[c];
    if (j < 60) {
        __shared__ float ctbj[DC];
        ctbj[c] = ws[WS_CTB + j * DC + c];
        __syncthreads();
        const float4* wq = (const float4*)(Wq + (size_t)c * DC);
        const float4* wk = (const float4*)(Wk + (size_t)c * DC);
        const float4* wv = (const float4*)(Wv + (size_t)c * DC);
        const float4* ct4 = (const float4*)ctbj;
        const float4* cb4 = (const float4*)cbL;
        float qc = 0.f, q0c = 0.f, kc = 0.f, kcbc = 0.f, gc = 0.f;
#pragma unroll 8
        for (int t = 0; t < 32; ++t) {
            const float4 a = wq[t], b = wk[t], g = wv[t], x = ct4[t], y = cb4[t];
            qc   += a.x * x.x + a.y * x.y + a.z * x.z + a.w * x.w;
            q0c  += a.x * y.x + a.y * y.y + a.z * y.z + a.w * y.w;
            kc   += b.x * x.x + b.y * x.y + b.z * x.z + b.w * x.w;
            kcbc += b.x * y.x + b.y * y.y + b.z * y.z + b.w * y.w;
            gc   += g.x * x.x + g.y * x.y + g.z * x.z + g.w * x.w;
        }
        ws[WS_QC + j * DC + c] = qc;
        ws[WS_KC + j * DC + c] = kc;
        ws[WS_G  + j * DC + c] = gc;
        const float beta = kcbc + bk[c];
        q0c += bq[c];
        float t1 = kc * q0c;        // -> s0[j]
        float t2 = qc * beta;       // -> bb[j]
#pragma unroll
        for (int off = 32; off > 0; off >>= 1) {
            t1 += __shfl_down(t1, off, 64);
            t2 += __shfl_down(t2, off, 64);
        }
        if ((c & 63) == 0) { red2a[c >> 6] = t1; red2b[c >> 6] = t2; }
        __syncthreads();
        if (c == 0) {
            ws[WS_S0 + j] = (red2a[0] + red2a[1]) * RSQRT_DC;
            ws[WS_BB + j] = (red2b[0] + red2b[1]) * RSQRT_DC;
        }
    } else {
        __syncthreads();
        const float4* wq = (const float4*)(Wq + (size_t)c * DC);
        const float4* wk = (const float4*)(Wk + (size_t)c * DC);
        const float4* wv = (const float4*)(Wv + (size_t)c * DC);
        const float4* cb4 = (const float4*)cbL;
        float q0c = 0.f, kcbc = 0.f, ob = 0.f;
#pragma unroll 8
        for (int t = 0; t < 32; ++t) {
            const float4 a = wq[t], b = wk[t], g = wv[t], y = cb4[t];
            q0c  += a.x * y.x + a.y * y.y + a.z * y.z + a.w * y.w;
            kcbc += b.x * y.x + b.y * y.y + b.z * y.z + b.w * y.w;
            ob   += g.x * y.x + g.y * y.y + g.z * y.z + g.w * y.w;
        }
        ws[WS_OUTB + c] = ob + bv[c];
        q0c += bq[c];
        float t1 = q0c * (kcbc + bk[c]);
#pragma unroll
        for (int off = 32; off > 0; off >>= 1) t1 += __shfl_down(t1, off, 64);
        if ((c & 63) == 0) red2a[c >> 6] = t1;
        __syncthreads();
        if (c == 0) ws[WS_B0] = (red2a[0] + red2a[1]) * RSQRT_DC;
    }
}

template <int NW>
__device__ __forceinline__ float bsum(float v, float* red, int tid) {
#pragma unroll
    for (int off = 32; off > 0; off >>= 1) v += __shfl_down(v, off, 64);
    if ((tid & 63) == 0) red[tid >> 6] = v;
    __syncthreads();
    float r = 0.f;
#pragma unroll
    for (int w = 0; w < NW; ++w) r += red[w];
    __syncthreads();
    return r;
}

// ---------------- K3: per-sequence encode ----------------
__global__ __launch_bounds__(512) void encode_kernel(
    const float* __restrict__ ws, float* __restrict__ out) {
    const int n = blockIdx.x, tid = threadIdx.x;
    const unsigned* packed = (const unsigned*)ws + WS_PACK;

    __shared__ unsigned tok2L[258];
    __shared__ float stabL[64];     // [60]=base
    __shared__ float cfL[60];       // counts * INV_LOUT
    __shared__ float uL[DC];
    __shared__ float Tt[1024];
    __shared__ float AccL[45];
    __shared__ float red[8];

    if (tid >= 64) {
        const int i = tid - 64;
        if (i < 258) tok2L[i] = (i < 256) ? packed[n * 256 + i] : 0u;
        else if (i < 258 + 45) AccL[i - 258] = 0.f;
    } else {
        // ===== wave0: cf -> u -> stab/base, wave-synchronous (no barriers) =====
        const int l = tid;
        const int4 ct = *(const int4*)((const int*)ws + WS_CNT + n * 4);
        const unsigned dwF = packed[n * 256];
        const unsigned dwL = packed[n * 256 + 255];
        if (l < KS) {
            const int k = l;
            const unsigned pm = (k == 0) ? 0u : ((1u << (2 * k)) - 1u);
            const unsigned sm = (k == 14) ? 0u : (0xFFFFFFFFu << (2 * (k + 2)));
            const int tot4[4] = {ct.x, ct.y, ct.z, ct.w};
#pragma unroll
            for (int v = 0; v < 4; ++v) {
                const unsigned patt = (unsigned)v * 0x55555555u;
                unsigned yf = dwF ^ patt, zf = (yf | (yf >> 1)) & 0x55555555u;
                unsigned yl = dwL ^ patt, zl = (yl | (yl >> 1)) & 0x55555555u;
                const int pre = k - __popc(zf & pm);
                const int suf = (14 - k) - __popc(zl & sm);
                cfL[v * KS + k] = (float)(tot4[v] - pre - suf) * INV_LOUT;
            }
        }
        // u[c] = sum_j cfL[j] * QC[j,c]   (2 cols/lane)
        const int c0 = 2 * l;
        float u0 = 0.f, u1 = 0.f;
        for (int j = 0; j < 60; ++j) {
            const float cfj = cfL[j];
            const float2 q2 = *(const float2*)(ws + WS_QC + j * DC + c0);
            u0 += cfj * q2.x; u1 += cfj * q2.y;
        }
        uL[c0] = u0; uL[c0 + 1] = u1;
        // base = b0 + bb . cf
        float t = (l < 60) ? cfL[l] * ws[WS_BB + l] : 0.f;
#pragma unroll
        for (int off = 32; off > 0; off >>= 1) t += __shfl_down(t, off, 64);
        if (l == 0) stabL[60] = ws[WS_B0] + t;
        // stab[j] = s0[j] + RSQRT_DC * (KC[j] . u)
        if (l < 60) {
            const float4* kr = (const float4*)(ws + WS_KC + (size_t)l * DC);
            const float4* u4 = (const float4*)uL;
            float s = 0.f;
#pragma unroll 8
            for (int t2 = 0; t2 < 32; ++t2) {
                const float4 a = kr[t2], u = u4[t2];
                s += a.x * u.x + a.y * u.y + a.z * u.z + a.w * u.w;
            }
            stabL[l] = ws[WS_S0 + l] + s * RSQRT_DC;
        }
    }
    __syncthreads();

    // ---- chunk tables ----
    const float base = stabL[60];
    for (int e = tid; e < 1024; e += 512) {
        const int j = e >> 8, bb = e & 255;
        float s = stabL[(bb & 3) * KS + 4 * j] +
                  stabL[((bb >> 2) & 3) * KS + 4 * j + 1] +
                  stabL[((bb >> 4) & 3) * KS + 4 * j + 2];
        if (j < 3) s += stabL[((bb >> 6) & 3) * KS + 4 * j + 3];
        Tt[e] = s;
    }
    // analytic upper bound on scores (exact max not needed for softmax)
    float M = base;
#pragma unroll
    for (int k = 0; k < KS; ++k)
        M += fmaxf(fmaxf(stabL[k], stabL[KS + k]),
                   fmaxf(stabL[2 * KS + k], stabL[3 * KS + k]));
    __syncthreads();

    // ---- scores -> e-values (registers only) ----
    const unsigned d0 = tok2L[tid >> 1], d1 = tok2L[(tid >> 1) + 1];
    const unsigned long long W = (unsigned long long)d0 | ((unsigned long long)d1 << 32);
    const int sbase = (tid & 1) << 4;
    const int t0 = tid * 8;
    float ev[8];
    float lsum = 0.f;
#pragma unroll
    for (int p = 0; p < 8; ++p) {
        const unsigned w = (unsigned)(W >> (sbase + 2 * p));
        const float s = base + Tt[w & 255] + Tt[256 + ((w >> 8) & 255)] +
                        Tt[512 + ((w >> 16) & 255)] + Tt[768 + ((w >> 24) & 63)];
        const float e = (t0 + p < LOUT) ? __expf(s - M) : 0.f;
        ev[p] = e; lsum += e;
    }
    const float S = bsum<8>(lsum, red, tid);
    const float invS = 1.0f / S;

    // ---- attn-weighted histogram (v=0 recovered from S) ----
    float a1[KS], a2[KS], a3[KS];
#pragma unroll
    for (int k = 0; k < KS; ++k) { a1[k] = 0.f; a2[k] = 0.f; a3[k] = 0.f; }
#pragma unroll
    for (int p = 0; p < 8; ++p) {
        const float e = ev[p];
        const unsigned w = (unsigned)(W >> (sbase + 2 * p));
#pragma unroll
        for (int k = 0; k < KS; ++k) {
            const int v = (int)((w >> (2 * k)) & 3u);
            a1[k] += (v == 1) ? e : 0.f;
            a2[k] += (v == 2) ? e : 0.f;
            a3[k] += (v == 3) ? e : 0.f;
        }
    }
    {
        const int lane = tid & 63;
#pragma unroll
        for (int k = 0; k < KS; ++k) {
            float v1 = a1[k], v2 = a2[k], v3 = a3[k];
#pragma unroll
            for (int off = 32; off > 0; off >>= 1) {
                v1 += __shfl_down(v1, off, 64);
                v2 += __shfl_down(v2, off, 64);
                v3 += __shfl_down(v3, off, 64);
            }
            if (lane == 0) {
                atomicAdd(&AccL[k], v1);
                atomicAdd(&AccL[KS + k], v2);
                atomicAdd(&AccL[2 * KS + k], v3);
            }
        }
    }
    __syncthreads();

    // ---- out[d] = outb[d] + invS * sum_j A_j * G[j,d] ----
    if (tid < DC) {
        float s = 0.f;
#pragma unroll
        for (int k = 0; k < KS; ++k) {
            const float a0 = S - AccL[k] - AccL[KS + k] - AccL[2 * KS + k];
            s += a0 * ws[WS_G + k * DC + tid];
        }
#pragma unroll
        for (int j = KS; j < 60; ++j) s += AccL[j - KS] * ws[WS_G + j * DC + tid];
        out[(size_t)n * DC + tid] = ws[WS_OUTB + tid] + s * invS;
    }
}

extern "C" void kernel_launch(void* const* d_in, const int* in_sizes, int n_in,
                              void* d_out, int out_size, void* d_ws, size_t ws_size,
                              hipStream_t stream) {
    const int*   tokens = (const int*)d_in[0];
    const float* emb    = (const float*)d_in[1];
    const float* conv_w = (const float*)d_in[2];
    const float* conv_b = (const float*)d_in[3];
    const float* Wq     = (const float*)d_in[4];
    const float* bq     = (const float*)d_in[5];
    const float* Wk     = (const float*)d_in[6];
    const float* bk     = (const float*)d_in[7];
    const float* Wv     = (const float*)d_in[8];
    const float* bv     = (const float*)d_in[9];
    float* out = (float*)d_out;
    float* ws  = (float*)d_ws;   // ~400 KB used

    prep1_kernel<<<NN + DC, 256, 0, stream>>>(tokens, emb, conv_w, ws);
    prep2_kernel<<<61, 128, 0, stream>>>(conv_b, Wq, bq, Wk, bk, Wv, bv, ws);
    encode_kernel<<<NN, 512, 0, stream>>>(ws, out);
}